// Round 14
// baseline (1908.734 us; speedup 1.0000x reference)
//

#include <hip/hip_runtime.h>
#include <hip/hip_bf16.h>

// The Python harness owns main(), I/O, device malloc/memcpy, and timing.
// You write only kernel_launch() (plus your __global__ kernels). The harness
// loads this file as a shared library, passes pre-populated device pointers,
// calls kernel_launch once for correctness, then graph-captures one call and
// replays the graph for timing, re-validating d_out afterwards.
//
// Launch ALL kernels on `stream` (<<<grid,block,0,stream>>>). hipMalloc /
// hipFree / synchronous hipMemcpy / hipDeviceSynchronize / hipEvent* will
// FAIL graph capture — use d_ws for scratch and hipMemcpyAsync(d2d, stream)
// if you need device-to-device copies. kernel_launch must do the same work
// on every call (no static guards / call-count checks).
//
// PNA GNN forward, 4 layers, N=50000 E=500000 d=64. fp32 internal pipeline.
// Float inputs/outputs may be bf16 or fp32 depending on harness variant; a
// device-side probe (kdt) detects the packing and all reads/writes branch on
// the device flag (uniform scalar branch, graph-capture safe).

#define ND 50000
#define NE 500000
typedef __hip_bfloat16 bh;
typedef unsigned short us;

__device__ float B2F(us u) { union { unsigned v; float f; } c; c.v = ((unsigned)u) << 16; return c.f; }
__device__ us F2B(float x) {
  union { float f; unsigned v; } c; c.f = x;
  unsigned r = c.v + 0x7fffu + ((c.v >> 16) & 1u);
  return (us)(r >> 16);
}
// load element i of a float tensor stored as bf16 (ib=1) or fp32 (ib=0)
__device__ float LD(const void* p, size_t i, int ib) {
  return ib ? B2F(((const us*)p)[i]) : ((const float*)p)[i];
}

// dtype probe: bf16-packed words have plausible bf16 values in their LOW
// halfword (~99% in (1e-3,100)); fp32 words have mantissa bits there (~7%).
__global__ void kdt(const unsigned* nf, int* fl) {
  __shared__ int cnt;
  if (threadIdx.x == 0) cnt = 0;
  __syncthreads();
  float v = B2F((us)(nf[threadIdx.x] & 0xffffu));
  float av = fabsf(v);
  if (av > 0.0009f && av < 100.f) atomicAdd(&cnt, 1);
  __syncthreads();
  if (threadIdx.x == 0) fl[0] = (cnt >= 128) ? 1 : 0;
}

// init: fp32 residual stream h = node_feat
__global__ void PNA_9826885173934_kernel(const void* nf, const int* fl, float* hf) {
  int ib = fl[0];
  int i = blockIdx.x * 256 + threadIdx.x;
  if (i < ND * 64) hf[i] = LD(nf, i, ib);
}

__global__ void kz(int* d) {
  int i = blockIdx.x * 256 + threadIdx.x;
  if (i < ND) d[i] = 0;
}

__global__ void kd(const int* ed, int* d) {
  int e = blockIdx.x * 256 + threadIdx.x;
  if (e < NE) { int t = ed[e]; if (t >= 0 && t < ND) atomicAdd(&d[t], 1); }
}

__global__ void ks(const int* d, int* rp, int* nx) {
  __shared__ int p[256];
  int t = threadIdx.x;
  const int CH = (ND + 255) / 256;
  int lo = t * CH, hi = lo + CH;
  if (hi > ND) hi = ND;
  int s = 0;
  for (int i = lo; i < hi; ++i) s += d[i];
  p[t] = s;
  __syncthreads();
  for (int o = 1; o < 256; o <<= 1) {
    int v = (t >= o) ? p[t - o] : 0;
    __syncthreads();
    p[t] += v;
    __syncthreads();
  }
  int run = p[t] - s;
  for (int i = lo; i < hi; ++i) { rp[i] = run; nx[i] = run; run += d[i]; }
  if (t == 255) rp[ND] = p[255];
}

__global__ void kc(const int* es, const int* ed, int* nx, int* ss) {
  int e = blockIdx.x * 256 + threadIdx.x;
  if (e < NE) {
    int t = ed[e];
    if (t >= 0 && t < ND) {
      int p = atomicAdd(&nx[t], 1);
      if (p >= 0 && p < NE) ss[p] = es[e];
    }
  }
}

// Wk[k][c], k<448, c<192 from WU rows [h|agg|agg*amp|agg*att] (1216x64):
// c<64: WU[k][c]; 64<=c<128: k>=64 ? WU[k+384][c-64] : 0; else k>=64 ? WU[k+768][c-128] : 0
__global__ void kp(const void* WU, int lo, const int* fl, float* Wk, float* st) {
  if (blockIdx.x == 0) st[threadIdx.x] = 0.f;
  int ib = fl[0];
  int i = blockIdx.x * 256 + threadIdx.x;
  if (i >= 448 * 192) return;
  int k = i / 192, c = i - k * 192;
  float o = 0.f;
  if (c < 64) o = LD(WU, (size_t)lo + (size_t)k * 64 + c, ib);
  else if (c < 128) { if (k >= 64) o = LD(WU, (size_t)lo + (size_t)(k + 384) * 64 + (c - 64), ib); }
  else { if (k >= 64) o = LD(WU, (size_t)lo + (size_t)(k + 768) * 64 + (c - 128), ib); }
  Wk[i] = o;
}

// ab[n][0:64] = h[n].WM[0:64]; ab[n][64:128] = h[n].WM[64:128] + bM
__global__ void ka(const float* hf, const void* WM, int lwm, const void* bM, int lb,
                   const int* fl, float* ab) {
  __shared__ float w[8192];
  int ib = fl[0];
  for (int t = threadIdx.x; t < 8192; t += 256) w[t] = LD(WM, (size_t)lwm + t, ib);
  __syncthreads();
  int j = threadIdx.x & 127, sb = threadIdx.x >> 7;
  int rb = (j < 64) ? 0 : 64, c = j & 63;
  float bi = (j >= 64) ? LD(bM, (size_t)lb + c, ib) : 0.f;
  for (int n = blockIdx.x * 2 + sb; n < ND; n += gridDim.x * 2) {
    const float* h = hf + (size_t)n * 64;
    float a = 0.f;
    for (int k = 0; k < 64; ++k) a += h[k] * w[(rb + k) * 64 + c];
    ab[(size_t)n * 128 + j] = a + bi;
  }
}

// X[n] = [h | mean | max | min | std | var | sum] fp32
__global__ void kg(const float* hf, const float* ab, const int* rp, const int* ss,
                   float* Xf, float* am, float* at) {
  int n = blockIdx.x * 4 + (threadIdx.x >> 6), c = threadIdx.x & 63;
  if (n >= ND) return;
  int r0 = rp[n], r1 = rp[n + 1];
  float bb = ab[(size_t)n * 128 + 64 + c];
  float s = 0.f, q = 0.f, mx = -3.4e38f, mn = 3.4e38f;
  for (int e = r0; e < r1; ++e) {
    int si = ss[e];
    if (si < 0 || si >= ND) si = 0;
    float v = ab[(size_t)si * 128 + c] + bb;
    s += v; q += v * v; mx = fmaxf(mx, v); mn = fminf(mn, v);
  }
  int dg = r1 - r0;
  float de = fmaxf((float)dg, 1.f);
  float me = s / de;
  float va = fmaxf(q / de - me * me, 0.f);
  float sd = sqrtf(va + 1e-30f);
  if (dg <= 0) { mx = 0.f; mn = 0.f; }
  size_t b = (size_t)n * 448;
  Xf[b + c] = hf[(size_t)n * 64 + c];
  Xf[b + 64 + c] = me;  Xf[b + 128 + c] = mx; Xf[b + 192 + c] = mn;
  Xf[b + 256 + c] = sd; Xf[b + 320 + c] = va; Xf[b + 384 + c] = s;
  if (c == 0) {
    float l = logf((float)dg + 1.f);
    am[n] = l * 0.4f;
    at[n] = (dg > 0) ? 2.5f / l : 0.f;
  }
}

// hu = (P0 + amp*P1 + att*P2 + bU)/sqrt(ND); st[0:64]=sum, st[64:128]=sumsq
__global__ void k1(const float* Xf, const float* Wk, const void* bU, int lb,
                   const int* fl, const float* am, const float* at,
                   float* hu, float* st) {
  __shared__ float sX[32][448];
  __shared__ float sr[128];
  int t = threadIdx.x;
  if (t < 128) sr[t] = 0.f;
  int ib = fl[0];
  int c = t & 63, sg = t >> 6, nb = blockIdx.x * 32;
  for (int i = t; i < 32 * 448; i += 256) {
    int r = i / 448, k = i - r * 448;
    int n = nb + r;
    if (n > ND - 1) n = ND - 1;
    sX[r][k] = Xf[(size_t)n * 448 + k];
  }
  __syncthreads();
  float a0[8], a1[8], a2[8];
  for (int r = 0; r < 8; ++r) { a0[r] = 0.f; a1[r] = 0.f; a2[r] = 0.f; }
  for (int k = 0; k < 448; ++k) {
    const float* w = Wk + (size_t)k * 192;
    float w0 = w[c], w1 = w[64 + c], w2 = w[128 + c];
    for (int r = 0; r < 8; ++r) {
      float x = sX[sg * 8 + r][k];
      a0[r] += x * w0; a1[r] += x * w1; a2[r] += x * w2;
    }
  }
  float bu = LD(bU, (size_t)lb + c, ib);
  float ps = 0.f, pq = 0.f;
  for (int r = 0; r < 8; ++r) {
    int n = nb + sg * 8 + r;
    if (n < ND) {
      float v = (a0[r] + am[n] * a1[r] + at[n] * a2[r] + bu) * 4.4721359549995794e-3f;
      hu[(size_t)n * 64 + c] = v;
      ps += v; pq += v * v;
    }
  }
  atomicAdd(&sr[c], ps);
  atomicAdd(&sr[64 + c], pq);
  __syncthreads();
  if (t < 128) atomicAdd(&st[t], sr[t]);
}

// BN_t -> @Wmix + bmix -> leaky(0.01) -> +h; st[128:256] = BN_o stats
__global__ void k2(const float* hu, float* st, const void* gt, const void* bt,
                   const void* Wm, const void* bm, int lb, int lw, const int* fl,
                   const float* hf, float* ob) {
  __shared__ float w[4096];
  __shared__ float sh2[4][64];
  __shared__ float rd[256];
  int ib = fl[0];
  int sb = threadIdx.x >> 6, c = threadIdx.x & 63;
  for (int t = threadIdx.x; t < 4096; t += 256) w[t] = LD(Wm, (size_t)lw + t, ib);
  float mu = st[c] * 2e-5f;
  float va = st[64 + c] * 2e-5f - mu * mu;
  float rs = rsqrtf(fmaxf(va, 0.f) + 1e-5f) * LD(gt, (size_t)lb + c, ib);
  float b0 = LD(bt, (size_t)lb + c, ib);
  float b1 = LD(bm, (size_t)lb + c, ib);
  float s = 0.f, q = 0.f;
  __syncthreads();
  int str = gridDim.x * 4;
  int it = (ND + str - 1) / str;
  for (int i = 0; i < it; ++i) {
    int n = i * str + blockIdx.x * 4 + sb;
    int ok = (n < ND) ? 1 : 0;
    float x = ok ? hu[(size_t)n * 64 + c] : 0.f;
    sh2[sb][c] = (x - mu) * rs + b0;
    __syncthreads();
    float a = 0.f;
    for (int k = 0; k < 64; ++k) a += sh2[sb][k] * w[k * 64 + c];
    a += b1;
    float hm = (a > 0.f) ? a : 0.01f * a;
    if (ok) {
      float o = hm + hf[(size_t)n * 64 + c];
      ob[(size_t)n * 64 + c] = o;
      s += o; q += o * o;
    }
    __syncthreads();
  }
  rd[threadIdx.x] = s;
  __syncthreads();
  if (sb == 0) atomicAdd(&st[128 + c], rd[c] + rd[c + 64] + rd[c + 128] + rd[c + 192]);
  __syncthreads();
  rd[threadIdx.x] = q;
  __syncthreads();
  if (sb == 0) atomicAdd(&st[192 + c], rd[c] + rd[c + 64] + rd[c + 128] + rd[c + 192]);
}

// h' = relu(BN_o(ob)) + h; writes hf and d_out (bf16 or fp32 per flag)
__global__ void k3(const float* ob, const float* st, const void* go, const void* bo,
                   int lb, const int* fl, float* hf, void* op) {
  int ib = fl[0];
  int i = blockIdx.x * 256 + threadIdx.x;
  if (i >= ND * 64) return;
  int c = i & 63;
  float mu = st[128 + c] * 2e-5f;
  float va = st[192 + c] * 2e-5f - mu * mu;
  float x = (ob[i] - mu) * rsqrtf(fmaxf(va, 0.f) + 1e-5f) * LD(go, (size_t)lb + c, ib)
            + LD(bo, (size_t)lb + c, ib);
  x = fmaxf(x, 0.f);
  float h = x + hf[i];
  hf[i] = h;
  if (ib) ((us*)op)[i] = F2B(h);
  else ((float*)op)[i] = h;
}

extern "C" void kernel_launch(void* const* d_in, const int* in_sizes, int n_in,
                              void* d_out, int out_size, void* d_ws, size_t ws_size,
                              hipStream_t stream) {
  int sh = (n_in >= 14) ? 0 : -1;
  const void* nf = d_in[0];
  const int* es = (const int*)d_in[2 + sh];
  const int* ed = (const int*)d_in[3 + sh];
  const void* WM = d_in[4 + sh];
  const void* bM = d_in[5 + sh];
  const void* WU = d_in[6 + sh];
  const void* bU = d_in[7 + sh];
  const void* gt = d_in[8 + sh];
  const void* bt = d_in[9 + sh];
  const void* Wm = d_in[10 + sh];
  const void* bm = d_in[11 + sh];
  const void* go = d_in[12 + sh];
  const void* bo = d_in[13 + sh];

  char* B = (char*)d_ws;
  float* hf = (float*)B;                       // 12.8 MB fp32 residual stream
  float* ab = (float*)(B + 12800000);          // 25.6 MB edge-projection pair
  float* Xf = (float*)(B + 38400000);          // 89.6 MB fp32 X
  size_t o0 = 38400000 + 89600000;
  float* am = (float*)(B + o0);
  float* at = (float*)(B + o0 + 200192);
  int* dg = (int*)(B + o0 + 400384);
  int* rp = (int*)(B + o0 + 600576);
  int* nx = (int*)(B + o0 + 800768);
  int* ss = (int*)(B + o0 + 1000960);
  float* Wk = (float*)(B + o0 + 3001088);
  float* st = (float*)(B + o0 + 3345152);
  int* fl = (int*)(B + o0 + 3346432);
  float* hu = ab;                              // ab dead after kg each layer
  float* ob = ab + (size_t)ND * 64;

  kdt<<<1, 256, 0, stream>>>((const unsigned*)nf, fl);
  PNA_9826885173934_kernel<<<(ND * 64 + 255) / 256, 256, 0, stream>>>(nf, fl, hf);
  kz<<<(ND + 255) / 256, 256, 0, stream>>>(dg);
  kd<<<(NE + 255) / 256, 256, 0, stream>>>(ed, dg);
  ks<<<1, 256, 0, stream>>>(dg, rp, nx);
  kc<<<(NE + 255) / 256, 256, 0, stream>>>(es, ed, nx, ss);

  for (int L = 0; L < 4; ++L) {
    kp<<<336, 256, 0, stream>>>(WU, L * 77824, fl, Wk, st);
    ka<<<1024, 256, 0, stream>>>(hf, WM, L * 8192, bM, L * 64, fl, ab);
    kg<<<(ND + 3) / 4, 256, 0, stream>>>(hf, ab, rp, ss, Xf, am, at);
    k1<<<(ND + 31) / 32, 256, 0, stream>>>(Xf, Wk, bU, L * 64, fl, am, at, hu, st);
    k2<<<800, 256, 0, stream>>>(hu, st, gt, bt, Wm, bm, L * 64, L * 4096, fl, hf, ob);
    k3<<<(ND * 64 + 255) / 256, 256, 0, stream>>>(ob, st, go, bo, L * 64, fl, hf, d_out);
  }
}

// Round 15
// 1461.838 us; speedup vs baseline: 1.3057x; 1.3057x over previous
//

#include <hip/hip_runtime.h>
#include <hip/hip_bf16.h>

// PNA GNN forward, 4 layers, N=50000 E=500000 d=64. fp32 internal pipeline.
// Float inputs/outputs may be bf16 or fp32 (device-side probe kdt detects).
// k1 (the dominant 448x192 GEMM) runs on MFMA via 3-term split-bf16:
// x*w ~= xh*wh + xh*wl + xl*wh (error ~2^-16 relative, fp32-class).

#define ND 50000
#define NE 500000
typedef __hip_bfloat16 bh;
typedef unsigned short us;
typedef __attribute__((ext_vector_type(8))) short short8;   // 8 bf16 (4 VGPRs)
typedef __attribute__((ext_vector_type(4))) float floatx4;
#define MFMA(a, b, c) __builtin_amdgcn_mfma_f32_16x16x32_bf16(a, b, c, 0, 0, 0)

__device__ float B2F(us u) { union { unsigned v; float f; } c; c.v = ((unsigned)u) << 16; return c.f; }
__device__ us F2B(float x) {
  union { float f; unsigned v; } c; c.f = x;
  unsigned r = c.v + 0x7fffu + ((c.v >> 16) & 1u);
  return (us)(r >> 16);
}
__device__ float LD(const void* p, size_t i, int ib) {
  return ib ? B2F(((const us*)p)[i]) : ((const float*)p)[i];
}
__device__ void SP(us* Xh, us* Xl, size_t i, float x) {
  us h = F2B(x);
  Xh[i] = h;
  Xl[i] = F2B(x - B2F(h));
}

// dtype probe: bf16-packed words have plausible bf16 values in the LOW
// halfword (~99% in (1e-3,100)); fp32 words have mantissa bits there (~7%).
__global__ void kdt(const unsigned* nf, int* fl) {
  __shared__ int cnt;
  if (threadIdx.x == 0) cnt = 0;
  __syncthreads();
  float v = B2F((us)(nf[threadIdx.x] & 0xffffu));
  float av = fabsf(v);
  if (av > 0.0009f && av < 100.f) atomicAdd(&cnt, 1);
  __syncthreads();
  if (threadIdx.x == 0) fl[0] = (cnt >= 128) ? 1 : 0;
}

// init: fp32 residual stream h = node_feat
__global__ void PNA_9826885173934_kernel(const void* nf, const int* fl, float* hf) {
  int ib = fl[0];
  int i = blockIdx.x * 256 + threadIdx.x;
  if (i < ND * 64) hf[i] = LD(nf, i, ib);
}

__global__ void kz(int* d) {
  int i = blockIdx.x * 256 + threadIdx.x;
  if (i < ND) d[i] = 0;
}

__global__ void kd(const int* ed, int* d) {
  int e = blockIdx.x * 256 + threadIdx.x;
  if (e < NE) { int t = ed[e]; if (t >= 0 && t < ND) atomicAdd(&d[t], 1); }
}

__global__ void ks(const int* d, int* rp, int* nx) {
  __shared__ int p[256];
  int t = threadIdx.x;
  const int CH = (ND + 255) / 256;
  int lo = t * CH, hi = lo + CH;
  if (hi > ND) hi = ND;
  int s = 0;
  for (int i = lo; i < hi; ++i) s += d[i];
  p[t] = s;
  __syncthreads();
  for (int o = 1; o < 256; o <<= 1) {
    int v = (t >= o) ? p[t - o] : 0;
    __syncthreads();
    p[t] += v;
    __syncthreads();
  }
  int run = p[t] - s;
  for (int i = lo; i < hi; ++i) { rp[i] = run; nx[i] = run; run += d[i]; }
  if (t == 255) rp[ND] = p[255];
}

__global__ void kc(const int* es, const int* ed, int* nx, int* ss) {
  int e = blockIdx.x * 256 + threadIdx.x;
  if (e < NE) {
    int t = ed[e];
    if (t >= 0 && t < ND) {
      int p = atomicAdd(&nx[t], 1);
      if (p >= 0 && p < NE) ss[p] = es[e];
    }
  }
}

// Wk split-bf16, [c][k] (B^T) layout: c<192, k<448 from WU rows
// [h|agg|agg*amp|agg*att] (1216x64):
// c<64: WU[k][c]; 64<=c<128: k>=64 ? WU[k+384][c-64] : 0; else k>=64 ? WU[k+768][c-128] : 0
__global__ void kp(const void* WU, int lo, const int* fl, us* Wkh, us* Wkl, float* st) {
  if (blockIdx.x == 0) st[threadIdx.x] = 0.f;
  int ib = fl[0];
  int i = blockIdx.x * 256 + threadIdx.x;
  if (i >= 192 * 448) return;
  int c = i / 448, k = i - c * 448;
  float o = 0.f;
  if (c < 64) o = LD(WU, (size_t)lo + (size_t)k * 64 + c, ib);
  else if (c < 128) { if (k >= 64) o = LD(WU, (size_t)lo + (size_t)(k + 384) * 64 + (c - 64), ib); }
  else { if (k >= 64) o = LD(WU, (size_t)lo + (size_t)(k + 768) * 64 + (c - 128), ib); }
  us h = F2B(o);
  Wkh[i] = h;
  Wkl[i] = F2B(o - B2F(h));
}

// ab[n][0:64] = h[n].WM[0:64]; ab[n][64:128] = h[n].WM[64:128] + bM
__global__ void ka(const float* hf, const void* WM, int lwm, const void* bM, int lb,
                   const int* fl, float* ab) {
  __shared__ float w[8192];
  int ib = fl[0];
  for (int t = threadIdx.x; t < 8192; t += 256) w[t] = LD(WM, (size_t)lwm + t, ib);
  __syncthreads();
  int j = threadIdx.x & 127, sb = threadIdx.x >> 7;
  int rb = (j < 64) ? 0 : 64, c = j & 63;
  float bi = (j >= 64) ? LD(bM, (size_t)lb + c, ib) : 0.f;
  for (int n = blockIdx.x * 2 + sb; n < ND; n += gridDim.x * 2) {
    const float* h = hf + (size_t)n * 64;
    float a = 0.f;
    for (int k = 0; k < 64; ++k) a += h[k] * w[(rb + k) * 64 + c];
    ab[(size_t)n * 128 + j] = a + bi;
  }
}

// X[n] = [h | mean | max | min | std | var | sum] -> split bf16 (Xh, Xl)
__global__ void kg(const float* hf, const float* ab, const int* rp, const int* ss,
                   us* Xh, us* Xl, float* am, float* at) {
  int n = blockIdx.x * 4 + (threadIdx.x >> 6), c = threadIdx.x & 63;
  if (n >= ND) return;
  int r0 = rp[n], r1 = rp[n + 1];
  float bb = ab[(size_t)n * 128 + 64 + c];
  float s = 0.f, q = 0.f, mx = -3.4e38f, mn = 3.4e38f;
  for (int e = r0; e < r1; ++e) {
    int si = ss[e];
    if (si < 0 || si >= ND) si = 0;
    float v = ab[(size_t)si * 128 + c] + bb;
    s += v; q += v * v; mx = fmaxf(mx, v); mn = fminf(mn, v);
  }
  int dg = r1 - r0;
  float de = fmaxf((float)dg, 1.f);
  float me = s / de;
  float va = fmaxf(q / de - me * me, 0.f);
  float sd = sqrtf(va + 1e-30f);
  if (dg <= 0) { mx = 0.f; mn = 0.f; }
  size_t b = (size_t)n * 448;
  SP(Xh, Xl, b + c, hf[(size_t)n * 64 + c]);
  SP(Xh, Xl, b + 64 + c, me);
  SP(Xh, Xl, b + 128 + c, mx);
  SP(Xh, Xl, b + 192 + c, mn);
  SP(Xh, Xl, b + 256 + c, sd);
  SP(Xh, Xl, b + 320 + c, va);
  SP(Xh, Xl, b + 384 + c, s);
  if (c == 0) {
    float l = logf((float)dg + 1.f);
    am[n] = l * 0.4f;
    at[n] = (dg > 0) ? 2.5f / l : 0.f;
  }
}

// MFMA GEMM: P = X(448) @ Wk^T (192 cols = P0|P1|P2), 3-term split-bf16.
// 32 nodes/block, 4 waves; wave w owns n-tiles {w, w+4, w+8} x both m-tiles,
// so P0/P1/P2 for the same output column land in the same lane (in-register
// amp/att combine). hu = (P0+amp*P1+att*P2+bU)/sqrt(ND); st[0:128] BN_t stats.
__global__ __launch_bounds__(256) void k1(
    const us* Xh, const us* Xl, const us* Wkh, const us* Wkl,
    const void* bU, int lb, const int* fl, const float* am, const float* at,
    float* hu, float* st) {
  __shared__ float sr[128];
  int t = threadIdx.x;
  if (t < 128) sr[t] = 0.f;
  __syncthreads();
  int ib = fl[0];
  int w = t >> 6, lane = t & 63;
  int quad = lane >> 4, l15 = lane & 15;
  int nb = blockIdx.x * 32;
  int n_a0 = nb + l15;       if (n_a0 > ND - 1) n_a0 = ND - 1;
  int n_a1 = nb + 16 + l15;  if (n_a1 > ND - 1) n_a1 = ND - 1;
  const size_t ra0 = (size_t)n_a0 * 448;
  const size_t ra1 = (size_t)n_a1 * 448;
  const size_t rb0 = (size_t)((w)     * 16 + l15) * 448;
  const size_t rb1 = (size_t)((w + 4) * 16 + l15) * 448;
  const size_t rb2 = (size_t)((w + 8) * 16 + l15) * 448;
  floatx4 ac[2][3] = {};
  for (int kk = 0; kk < 14; ++kk) {
    int ko = kk * 32 + quad * 8;
    short8 a0h = *(const short8*)&Xh[ra0 + ko];
    short8 a0l = *(const short8*)&Xl[ra0 + ko];
    short8 a1h = *(const short8*)&Xh[ra1 + ko];
    short8 a1l = *(const short8*)&Xl[ra1 + ko];
    short8 b0h = *(const short8*)&Wkh[rb0 + ko];
    short8 b0l = *(const short8*)&Wkl[rb0 + ko];
    short8 b1h = *(const short8*)&Wkh[rb1 + ko];
    short8 b1l = *(const short8*)&Wkl[rb1 + ko];
    short8 b2h = *(const short8*)&Wkh[rb2 + ko];
    short8 b2l = *(const short8*)&Wkl[rb2 + ko];
    ac[0][0] = MFMA(a0h, b0h, ac[0][0]);
    ac[0][0] = MFMA(a0h, b0l, ac[0][0]);
    ac[0][0] = MFMA(a0l, b0h, ac[0][0]);
    ac[0][1] = MFMA(a0h, b1h, ac[0][1]);
    ac[0][1] = MFMA(a0h, b1l, ac[0][1]);
    ac[0][1] = MFMA(a0l, b1h, ac[0][1]);
    ac[0][2] = MFMA(a0h, b2h, ac[0][2]);
    ac[0][2] = MFMA(a0h, b2l, ac[0][2]);
    ac[0][2] = MFMA(a0l, b2h, ac[0][2]);
    ac[1][0] = MFMA(a1h, b0h, ac[1][0]);
    ac[1][0] = MFMA(a1h, b0l, ac[1][0]);
    ac[1][0] = MFMA(a1l, b0h, ac[1][0]);
    ac[1][1] = MFMA(a1h, b1h, ac[1][1]);
    ac[1][1] = MFMA(a1h, b1l, ac[1][1]);
    ac[1][1] = MFMA(a1l, b1h, ac[1][1]);
    ac[1][2] = MFMA(a1h, b2h, ac[1][2]);
    ac[1][2] = MFMA(a1h, b2l, ac[1][2]);
    ac[1][2] = MFMA(a1l, b2h, ac[1][2]);
  }
  // D layout: col = lane&15 (within n-tile), row = quad*4 + r (within m-tile)
  int c = w * 16 + l15;   // P0 column index (0..63)
  float bu = LD(bU, (size_t)lb + c, ib);
  float ps = 0.f, pq = 0.f;
  for (int mt = 0; mt < 2; ++mt) {
    for (int r = 0; r < 4; ++r) {
      int node = nb + mt * 16 + quad * 4 + r;
      if (node < ND) {
        float v = (ac[mt][0][r] + am[node] * ac[mt][1][r] + at[node] * ac[mt][2][r] + bu)
                  * 4.4721359549995794e-3f;   // 1/sqrt(50000)
        hu[(size_t)node * 64 + c] = v;
        ps += v; pq += v * v;
      }
    }
  }
  atomicAdd(&sr[c], ps);
  atomicAdd(&sr[64 + c], pq);
  __syncthreads();
  if (t < 128) atomicAdd(&st[t], sr[t]);
}

// BN_t -> @Wmix + bmix -> leaky(0.01) -> +h; st[128:256] = BN_o stats
__global__ void k2(const float* hu, float* st, const void* gt, const void* bt,
                   const void* Wm, const void* bm, int lb, int lw, const int* fl,
                   const float* hf, float* ob) {
  __shared__ float w[4096];
  __shared__ float sh2[4][64];
  __shared__ float rd[256];
  int ib = fl[0];
  int sb = threadIdx.x >> 6, c = threadIdx.x & 63;
  for (int t = threadIdx.x; t < 4096; t += 256) w[t] = LD(Wm, (size_t)lw + t, ib);
  float mu = st[c] * 2e-5f;
  float va = st[64 + c] * 2e-5f - mu * mu;
  float rs = rsqrtf(fmaxf(va, 0.f) + 1e-5f) * LD(gt, (size_t)lb + c, ib);
  float b0 = LD(bt, (size_t)lb + c, ib);
  float b1 = LD(bm, (size_t)lb + c, ib);
  float s = 0.f, q = 0.f;
  __syncthreads();
  int str = gridDim.x * 4;
  int it = (ND + str - 1) / str;
  for (int i = 0; i < it; ++i) {
    int n = i * str + blockIdx.x * 4 + sb;
    int ok = (n < ND) ? 1 : 0;
    float x = ok ? hu[(size_t)n * 64 + c] : 0.f;
    sh2[sb][c] = (x - mu) * rs + b0;
    __syncthreads();
    float a = 0.f;
    for (int k = 0; k < 64; ++k) a += sh2[sb][k] * w[k * 64 + c];
    a += b1;
    float hm = (a > 0.f) ? a : 0.01f * a;
    if (ok) {
      float o = hm + hf[(size_t)n * 64 + c];
      ob[(size_t)n * 64 + c] = o;
      s += o; q += o * o;
    }
    __syncthreads();
  }
  rd[threadIdx.x] = s;
  __syncthreads();
  if (sb == 0) atomicAdd(&st[128 + c], rd[c] + rd[c + 64] + rd[c + 128] + rd[c + 192]);
  __syncthreads();
  rd[threadIdx.x] = q;
  __syncthreads();
  if (sb == 0) atomicAdd(&st[192 + c], rd[c] + rd[c + 64] + rd[c + 128] + rd[c + 192]);
}

// h' = relu(BN_o(ob)) + h; writes hf and d_out (bf16 or fp32 per flag)
__global__ void k3(const float* ob, const float* st, const void* go, const void* bo,
                   int lb, const int* fl, float* hf, void* op) {
  int ib = fl[0];
  int i = blockIdx.x * 256 + threadIdx.x;
  if (i >= ND * 64) return;
  int c = i & 63;
  float mu = st[128 + c] * 2e-5f;
  float va = st[192 + c] * 2e-5f - mu * mu;
  float x = (ob[i] - mu) * rsqrtf(fmaxf(va, 0.f) + 1e-5f) * LD(go, (size_t)lb + c, ib)
            + LD(bo, (size_t)lb + c, ib);
  x = fmaxf(x, 0.f);
  float h = x + hf[i];
  hf[i] = h;
  if (ib) ((us*)op)[i] = F2B(h);
  else ((float*)op)[i] = h;
}

extern "C" void kernel_launch(void* const* d_in, const int* in_sizes, int n_in,
                              void* d_out, int out_size, void* d_ws, size_t ws_size,
                              hipStream_t stream) {
  int sh = (n_in >= 14) ? 0 : -1;
  const void* nf = d_in[0];
  const int* es = (const int*)d_in[2 + sh];
  const int* ed = (const int*)d_in[3 + sh];
  const void* WM = d_in[4 + sh];
  const void* bM = d_in[5 + sh];
  const void* WU = d_in[6 + sh];
  const void* bU = d_in[7 + sh];
  const void* gt = d_in[8 + sh];
  const void* bt = d_in[9 + sh];
  const void* Wm = d_in[10 + sh];
  const void* bm = d_in[11 + sh];
  const void* go = d_in[12 + sh];
  const void* bo = d_in[13 + sh];

  char* B = (char*)d_ws;
  float* hf = (float*)B;                       // 12.8 MB fp32 residual stream
  float* ab = (float*)(B + 12800000);          // 25.6 MB edge-projection pair
  us* Xh = (us*)(B + 38400000);                // 44.8 MB split-bf16 X hi
  us* Xl = (us*)(B + 83200000);                // 44.8 MB split-bf16 X lo
  size_t o0 = 128000000;
  float* am = (float*)(B + o0);
  float* at = (float*)(B + o0 + 200192);
  int* dg = (int*)(B + o0 + 400384);
  int* rp = (int*)(B + o0 + 600576);
  int* nx = (int*)(B + o0 + 800768);
  int* ss = (int*)(B + o0 + 1000960);
  us* Wkh = (us*)(B + o0 + 3001088);           // 172032 B
  us* Wkl = (us*)(B + o0 + 3173120);           // 172032 B
  float* st = (float*)(B + o0 + 3345152);
  int* fl = (int*)(B + o0 + 3346432);
  float* hu = ab;                              // ab dead after kg each layer
  float* ob = ab + (size_t)ND * 64;

  kdt<<<1, 256, 0, stream>>>((const unsigned*)nf, fl);
  PNA_9826885173934_kernel<<<(ND * 64 + 255) / 256, 256, 0, stream>>>(nf, fl, hf);
  kz<<<(ND + 255) / 256, 256, 0, stream>>>(dg);
  kd<<<(NE + 255) / 256, 256, 0, stream>>>(ed, dg);
  ks<<<1, 256, 0, stream>>>(dg, rp, nx);
  kc<<<(NE + 255) / 256, 256, 0, stream>>>(es, ed, nx, ss);

  for (int L = 0; L < 4; ++L) {
    kp<<<336, 256, 0, stream>>>(WU, L * 77824, fl, Wkh, Wkl, st);
    ka<<<1024, 256, 0, stream>>>(hf, WM, L * 8192, bM, L * 64, fl, ab);
    kg<<<(ND + 3) / 4, 256, 0, stream>>>(hf, ab, rp, ss, Xh, Xl, am, at);
    k1<<<(ND + 31) / 32, 256, 0, stream>>>(Xh, Xl, Wkh, Wkl, bU, L * 64, fl, am, at, hu, st);
    k2<<<800, 256, 0, stream>>>(hu, st, gt, bt, Wm, bm, L * 64, L * 4096, fl, hf, ob);
    k3<<<(ND * 64 + 255) / 256, 256, 0, stream>>>(ob, st, go, bo, L * 64, fl, hf, d_out);
  }
}